// Round 9
// baseline (459.318 us; speedup 1.0000x reference)
//
#include <hip/hip_runtime.h>
#include <math.h>

#define N_NODES 50000
#define N_EDGES 800000
#define OUTC 40
#define N_BATCH 10000
#define H2S 48     // padded stride for h2 (bf16 elements)
#define BKT 64     // bucket slots per node (deg mean 16, sigma 4 -> 64 is ~12 sigma)

typedef float f32x4 __attribute__((ext_vector_type(4)));
typedef short s16x8 __attribute__((ext_vector_type(8)));
typedef short s16x4 __attribute__((ext_vector_type(4)));

union Frag { s16x8 v; s16x4 h[2]; };

__device__ inline unsigned short f2bf(float f) {
    unsigned int u = __float_as_uint(f);
    u += 0x7fff + ((u >> 16) & 1);           // round-to-nearest-even
    return (unsigned short)(u >> 16);
}
__device__ inline float lo16(unsigned int u) { return __uint_as_float(u << 16); }
__device__ inline float hi16(unsigned int u) { return __uint_as_float(u & 0xffff0000u); }
__device__ inline unsigned int pk2(float a, float b) {
    return (unsigned int)f2bf(a) | ((unsigned int)f2bf(b) << 16);
}
__device__ inline void unpk8(uint4 u, float* f) {   // 8 packed bf16 -> 8 fp32
    f[0] = lo16(u.x); f[1] = hi16(u.x);
    f[2] = lo16(u.y); f[3] = hi16(u.y);
    f[4] = lo16(u.z); f[5] = hi16(u.z);
    f[6] = lo16(u.w); f[7] = hi16(u.w);
}

// ---------------- fused init: W1T transpose + zero cur + zero stats ----------------
__global__ __launch_bounds__(256) void init_kernel(const float* __restrict__ W1,
                                                   unsigned short* __restrict__ W1T,
                                                   int* __restrict__ cur,
                                                   float* __restrict__ stats) {
    int b = blockIdx.x, t = threadIdx.x;
    if (b < 256) {
        // W1 [256k][256n] fp32 -> W1T bf16 [256n][256k]
        W1T[(size_t)t * 256 + b] = f2bf(W1[(size_t)b * 256 + t]);
    } else if (b < 256 + 196) {
        int i = (b - 256) * 256 + t;
        if (i < N_NODES) cur[i] = 0;
    } else {
        for (int i = t; i < 1024; i += 256) stats[i] = 0.f;
    }
}

// ---------------- bucket scatter: cur[d] = degree, srcs[d*64+j] = j-th source (ushort) ----------------
// ushort srcs halves the bucket footprint (6.4MB) and the dirty-line count per node
__global__ __launch_bounds__(256) void scatter_kernel(const int* __restrict__ ei,
                                                      int* __restrict__ cur,
                                                      unsigned short* __restrict__ srcs) {
    int e = blockIdx.x * 256 + threadIdx.x;
    if (e >= N_EDGES) return;
    int d = ei[N_EDGES + e];
    int pos = atomicAdd(&cur[d], 1);
    if (pos < BKT) srcs[(size_t)d * BKT + pos] = (unsigned short)ei[e];
}

// ---------------- GEMM1 MFMA: h1 = bf16(feat @ W1 + b1), output bf16 ----------------
// round-7 proven version: 128x128 tiles, grid (391,2), 782 blocks
#define LDA 40
__global__ __launch_bounds__(256) void gemm1_mfma(const float* __restrict__ A,
                                                  const unsigned short* __restrict__ BT,
                                                  const float* __restrict__ bias,
                                                  unsigned short* __restrict__ C) {
    __shared__ unsigned short As[128 * LDA];
    __shared__ unsigned short Bs[128 * LDA];
    int t = threadIdx.x;
    int lane = t & 63, wave = t >> 6;
    int ln = lane & 15, quad = lane >> 4;
    int row0 = blockIdx.x * 128;
    int col0 = blockIdx.y * 128;
    int m0 = (wave & 1) * 64, n0 = (wave >> 1) * 64;
    f32x4 acc[4][4];
    #pragma unroll
    for (int i = 0; i < 4; i++)
        #pragma unroll
        for (int j = 0; j < 4; j++) acc[i][j] = (f32x4){0.f, 0.f, 0.f, 0.f};
    int r = t >> 1, half = t & 1;

    for (int k0 = 0; k0 < 256; k0 += 32) {
        {
            int gr = row0 + r;
            float4 v[4];
            if (gr < N_NODES) {
                const float4* src = (const float4*)(A + (size_t)gr * 256 + k0 + half * 16);
                v[0] = src[0]; v[1] = src[1]; v[2] = src[2]; v[3] = src[3];
            } else {
                float4 z = make_float4(0.f, 0.f, 0.f, 0.f);
                v[0] = z; v[1] = z; v[2] = z; v[3] = z;
            }
            ushort4* dst = (ushort4*)&As[r * LDA + half * 16];
            #pragma unroll
            for (int q = 0; q < 4; q++) {
                ushort4 u;
                u.x = f2bf(v[q].x); u.y = f2bf(v[q].y);
                u.z = f2bf(v[q].z); u.w = f2bf(v[q].w);
                dst[q] = u;
            }
        }
        {
            const ushort4* src = (const ushort4*)(BT + (size_t)(col0 + r) * 256 + k0 + half * 16);
            ushort4* dst = (ushort4*)&Bs[r * LDA + half * 16];
            dst[0] = src[0]; dst[1] = src[1]; dst[2] = src[2]; dst[3] = src[3];
        }
        __syncthreads();
        Frag af[4], bf[4];
        #pragma unroll
        for (int i = 0; i < 4; i++) {
            int ar = m0 + i * 16 + ln;
            af[i].h[0] = *(const s16x4*)&As[ar * LDA + quad * 8];
            af[i].h[1] = *(const s16x4*)&As[ar * LDA + quad * 8 + 4];
            int br = n0 + i * 16 + ln;
            bf[i].h[0] = *(const s16x4*)&Bs[br * LDA + quad * 8];
            bf[i].h[1] = *(const s16x4*)&Bs[br * LDA + quad * 8 + 4];
        }
        #pragma unroll
        for (int i = 0; i < 4; i++)
            #pragma unroll
            for (int j = 0; j < 4; j++)
                acc[i][j] = __builtin_amdgcn_mfma_f32_16x16x32_bf16(af[i].v, bf[j].v, acc[i][j], 0, 0, 0);
        __syncthreads();
    }
    #pragma unroll
    for (int j = 0; j < 4; j++) {
        int gc = col0 + n0 + j * 16 + ln;
        float bv = bias[gc];
        #pragma unroll
        for (int i = 0; i < 4; i++) {
            int gb = row0 + m0 + i * 16 + quad * 4;
            #pragma unroll
            for (int rg = 0; rg < 4; rg++) {
                int gr = gb + rg;
                if (gr < N_NODES) C[(size_t)gr * 256 + gc] = f2bf(acc[i][j][rg] + bv);
            }
        }
    }
}

// ---------------- agg1: wave per node, 4 edge-slots x 16 lanes (round-0 body) ----------------
__global__ __launch_bounds__(256) void agg1_kernel(const unsigned short* __restrict__ h,
                                                   const int* __restrict__ degp,
                                                   const unsigned short* __restrict__ srcs,
                                                   const float* __restrict__ gamma_p,
                                                   unsigned short* __restrict__ x1) {
    int lane = threadIdx.x & 63;
    int node = blockIdx.x * 4 + (threadIdx.x >> 6);
    if (node >= N_NODES) return;
    int eslot = lane >> 4, cgrp = lane & 15;
    float g = gamma_p[0];
    float hd[16];
    {
        const uint4* hrow = (const uint4*)(h + (size_t)node * 256 + cgrp * 16);
        uint4 u0 = hrow[0], u1 = hrow[1];
        unpk8(u0, hd); unpk8(u1, hd + 8);
    }
    float acc[16];
    #pragma unroll
    for (int c = 0; c < 16; c++) acc[c] = 0.f;
    float den = 0.f;
    int beg = node << 6;
    int end = beg + degp[node];
    int n_it = (end - beg + 3) >> 2;
    for (int it = 0; it < n_it; it++) {
        int i = beg + it * 4 + eslot;
        bool valid = i < end;
        int s = valid ? (int)srcs[i] : node;
        const uint4* arow = (const uint4*)(h + (size_t)s * 256 + cgrp * 16);
        uint4 u0 = arow[0], u1 = arow[1];
        float av[16];
        unpk8(u0, av); unpk8(u1, av + 8);
        float d2 = 0.f;
        #pragma unroll
        for (int c = 0; c < 16; c++) { float d = av[c] - hd[c]; d2 = fmaf(d, d, d2); }
        d2 += __shfl_xor(d2, 1, 64);
        d2 += __shfl_xor(d2, 2, 64);
        d2 += __shfl_xor(d2, 4, 64);
        d2 += __shfl_xor(d2, 8, 64);
        float w = valid ? __expf(-g * d2) : 0.f;
        den += w;
        #pragma unroll
        for (int c = 0; c < 16; c++) acc[c] = fmaf(w, av[c], acc[c]);
    }
    #pragma unroll
    for (int m = 16; m < 64; m <<= 1) {
        den += __shfl_xor(den, m, 64);
        #pragma unroll
        for (int c = 0; c < 16; c++) acc[c] += __shfl_xor(acc[c], m, 64);
    }
    if (eslot == 0) {
        float inv = 1.f / (den + 1e-16f);
        float vv[16];
        #pragma unroll
        for (int c = 0; c < 16; c++) vv[c] = acc[c] * inv;
        uint4 oA = make_uint4(pk2(vv[0], vv[1]), pk2(vv[2], vv[3]),
                              pk2(vv[4], vv[5]), pk2(vv[6], vv[7]));
        uint4 oB = make_uint4(pk2(vv[8], vv[9]), pk2(vv[10], vv[11]),
                              pk2(vv[12], vv[13]), pk2(vv[14], vv[15]));
        uint4* o4 = (uint4*)(x1 + (size_t)node * 256 + cgrp * 16);
        o4[0] = oA; o4[1] = oB;
    }
}

// ---------------- per-channel stats, C=256, bf16 input ----------------
// thread t covers channels (t&127)*2..+1 of row-pair; 2 rows/iteration, grid 1024
__global__ __launch_bounds__(256) void stats1_kernel(const unsigned short* __restrict__ x,
                                                     float* __restrict__ sum,
                                                     float* __restrict__ sumsq) {
    int t = threadIdx.x;
    int c2 = (t & 127) * 2;          // channel pair
    int rsub = t >> 7;               // 0 or 1: which row of the pair
    float s0 = 0.f, q0 = 0.f, s1 = 0.f, q1 = 0.f;
    for (int r = blockIdx.x * 2 + rsub; r < N_NODES; r += gridDim.x * 2) {
        unsigned int u = *(const unsigned int*)(x + (size_t)r * 256 + c2);
        float v0 = lo16(u), v1 = hi16(u);
        s0 += v0; q0 += v0 * v0;
        s1 += v1; q1 += v1 * v1;
    }
    atomicAdd(&sum[c2], s0);
    atomicAdd(&sumsq[c2], q0);
    atomicAdd(&sum[c2 + 1], s1);
    atomicAdd(&sumsq[c2 + 1], q1);
}

// ---------------- GEMM2 + fused BN1/ReLU: h2 bf16(stride 48) = relu(bn(x1)) @ W2 + b2 ----------------
__global__ __launch_bounds__(256) void gemm2_kernel(const unsigned short* __restrict__ X,
                                                    const float* __restrict__ W2,
                                                    const float* __restrict__ bias,
                                                    const float* __restrict__ sum1,
                                                    const float* __restrict__ sumsq1,
                                                    const float* __restrict__ bg,
                                                    const float* __restrict__ bb,
                                                    unsigned short* __restrict__ H) {
    __shared__ float W2s[40 * 260];
    __shared__ float aas[256], bbs[256];
    int t = threadIdx.x;
    // coalesced staging: linear global read, scattered LDS write
    for (int i = t; i < 256 * 40; i += 256) {
        int k = i / 40, c = i % 40;       // W2 is [256k][40c] row-major
        W2s[c * 260 + k] = W2[i];
    }
    {
        const float invN = 1.f / N_NODES;
        float mu = sum1[t] * invN;
        float var = sumsq1[t] * invN - mu * mu;
        float rs = rsqrtf(var + 1e-5f) * bg[t];
        aas[t] = rs;
        bbs[t] = bb[t] - mu * rs;
    }
    __syncthreads();
    int slot = t >> 2, cg = t & 3;
    int rbase = blockIdx.x * 256 + slot;
    const uint2* xp[4];
    #pragma unroll
    for (int rr = 0; rr < 4; rr++) xp[rr] = (const uint2*)(X + (size_t)(rbase + rr * 64) * 256);
    float acc[4][10];
    #pragma unroll
    for (int rr = 0; rr < 4; rr++)
        #pragma unroll
        for (int i = 0; i < 10; i++) acc[rr][i] = 0.f;

    for (int k4 = 0; k4 < 64; k4++) {
        int k = k4 * 4;
        float4 a4 = *(const float4*)&aas[k];
        float4 b4 = *(const float4*)&bbs[k];
        float4 w4[10];
        #pragma unroll
        for (int i = 0; i < 10; i++) w4[i] = *(const float4*)&W2s[(cg * 10 + i) * 260 + k];
        #pragma unroll
        for (int rr = 0; rr < 4; rr++) {
            uint2 xu = xp[rr][k4];
            float y0 = fmaxf(fmaf(lo16(xu.x), a4.x, b4.x), 0.f);
            float y1 = fmaxf(fmaf(hi16(xu.x), a4.y, b4.y), 0.f);
            float y2 = fmaxf(fmaf(lo16(xu.y), a4.z, b4.z), 0.f);
            float y3 = fmaxf(fmaf(hi16(xu.y), a4.w, b4.w), 0.f);
            #pragma unroll
            for (int i = 0; i < 10; i++)
                acc[rr][i] += y0 * w4[i].x + y1 * w4[i].y + y2 * w4[i].z + y3 * w4[i].w;
        }
    }
    #pragma unroll
    for (int rr = 0; rr < 4; rr++) {
        int row = rbase + rr * 64;
        if (row < N_NODES) {
            float y[10];
            #pragma unroll
            for (int i = 0; i < 10; i++) y[i] = acc[rr][i] + bias[cg * 10 + i];
            unsigned int* o32 = (unsigned int*)(H + (size_t)row * H2S + cg * 10);
            #pragma unroll
            for (int i = 0; i < 5; i++) o32[i] = pk2(y[2 * i], y[2 * i + 1]);
            if (cg == 1)
                *(uint4*)(H + (size_t)row * H2S + 40) = make_uint4(0, 0, 0, 0);
        }
    }
}

// ---------------- agg2: 2 nodes per wave (half-wave = 4 edge-slots x 8 lanes) ----------------
__global__ __launch_bounds__(256) void agg2_kernel(const unsigned short* __restrict__ h,
                                                   const int* __restrict__ degp,
                                                   const unsigned short* __restrict__ srcs,
                                                   const float* __restrict__ gamma_p,
                                                   float* __restrict__ x2) {
    int l32 = threadIdx.x & 31;
    int node = blockIdx.x * 8 + (threadIdx.x >> 5);
    if (node >= N_NODES) return;
    int eslot = l32 >> 3, cgrp = l32 & 7;
    float g = gamma_p[0];
    float hd[6];
    {
        const unsigned int* hrow = (const unsigned int*)(h + (size_t)node * H2S + cgrp * 6);
        unsigned int u0 = hrow[0], u1 = hrow[1], u2 = hrow[2];
        hd[0] = lo16(u0); hd[1] = hi16(u0);
        hd[2] = lo16(u1); hd[3] = hi16(u1);
        hd[4] = lo16(u2); hd[5] = hi16(u2);
    }
    float acc[6] = {0.f, 0.f, 0.f, 0.f, 0.f, 0.f};
    float den = 0.f;
    int beg = node << 6;
    int end = beg + degp[node];
    int n_it = (end - beg + 3) >> 2;
    for (int it = 0; it < n_it; it++) {
        int i = beg + it * 4 + eslot;
        bool valid = i < end;
        int s = valid ? (int)srcs[i] : node;
        const unsigned int* arow = (const unsigned int*)(h + (size_t)s * H2S + cgrp * 6);
        unsigned int u0 = arow[0], u1 = arow[1], u2 = arow[2];
        float av[6];
        av[0] = lo16(u0); av[1] = hi16(u0);
        av[2] = lo16(u1); av[3] = hi16(u1);
        av[4] = lo16(u2); av[5] = hi16(u2);
        float d2 = 0.f;
        #pragma unroll
        for (int j = 0; j < 6; j++) { float d = av[j] - hd[j]; d2 = fmaf(d, d, d2); }
        d2 += __shfl_xor(d2, 1, 64);    // within 8-lane cgrp group
        d2 += __shfl_xor(d2, 2, 64);
        d2 += __shfl_xor(d2, 4, 64);
        float w = valid ? __expf(-g * d2) : 0.f;
        den += w;
        #pragma unroll
        for (int j = 0; j < 6; j++) acc[j] = fmaf(w, av[j], acc[j]);
    }
    // reduce across the 4 edge-slots of this half-wave (masks 8,16 stay in-half)
    #pragma unroll
    for (int m = 8; m < 32; m <<= 1) {
        den += __shfl_xor(den, m, 64);
        #pragma unroll
        for (int j = 0; j < 6; j++) acc[j] += __shfl_xor(acc[j], m, 64);
    }
    if (eslot == 0) {
        float inv = 1.f / (den + 1e-16f);
        int cb = cgrp * 6;
        #pragma unroll
        for (int j = 0; j < 6; j++)
            if (cb + j < OUTC) x2[(size_t)node * OUTC + cb + j] = acc[j] * inv;
    }
}

// ---------------- per-channel stats, C=40 ----------------
__global__ __launch_bounds__(256) void stats2_kernel(const float* __restrict__ x,
                                                     float* __restrict__ sum,
                                                     float* __restrict__ sumsq) {
    int c = threadIdx.x;
    if (c >= OUTC) return;
    float s = 0.f, s2 = 0.f;
    for (int r = blockIdx.x * 4 + threadIdx.y; r < N_NODES; r += gridDim.x * 4) {
        float v = x[(size_t)r * OUTC + c];
        s += v;
        s2 += v * v;
    }
    atomicAdd(&sum[c], s);
    atomicAdd(&sumsq[c], s2);
}

// ---------------- BN2 + ReLU + gather + log_softmax ----------------
__global__ __launch_bounds__(256) void final_kernel(const float* __restrict__ x2,
                                                    const float* __restrict__ sum,
                                                    const float* __restrict__ sumsq,
                                                    const float* __restrict__ g,
                                                    const float* __restrict__ b,
                                                    const int* __restrict__ batch,
                                                    float* __restrict__ out) {
    int lane = threadIdx.x & 63;
    int row = blockIdx.x * 4 + (threadIdx.x >> 6);
    if (row >= N_BATCH) return;
    int node = batch[row];
    bool act = lane < OUTC;
    float v = -INFINITY;
    if (act) {
        const float invN = 1.f / N_NODES;
        float mu = sum[lane] * invN;
        float var = sumsq[lane] * invN - mu * mu;
        float xv = x2[(size_t)node * OUTC + lane];
        float y = (xv - mu) * rsqrtf(var + 1e-5f) * g[lane] + b[lane];
        v = fmaxf(y, 0.f);
    }
    float m = v;
    #pragma unroll
    for (int s = 1; s < 64; s <<= 1) m = fmaxf(m, __shfl_xor(m, s, 64));
    float p = act ? expf(v - m) : 0.f;
    float ssum = p;
    #pragma unroll
    for (int s = 1; s < 64; s <<= 1) ssum += __shfl_xor(ssum, s, 64);
    if (act) out[(size_t)row * OUTC + lane] = v - m - logf(ssum);
}

extern "C" void kernel_launch(void* const* d_in, const int* in_sizes, int n_in,
                              void* d_out, int out_size, void* d_ws, size_t ws_size,
                              hipStream_t stream) {
    const float* feat   = (const float*)d_in[0];
    const int*   ei     = (const int*)d_in[1];
    const int*   batch  = (const int*)d_in[2];
    const float* W1     = (const float*)d_in[3];
    const float* b1     = (const float*)d_in[4];
    const float* gamma1 = (const float*)d_in[5];
    const float* W2     = (const float*)d_in[6];
    const float* b2     = (const float*)d_in[7];
    const float* gamma2 = (const float*)d_in[8];
    const float* bn1w   = (const float*)d_in[9];
    const float* bn1b   = (const float*)d_in[10];
    const float* bn2w   = (const float*)d_in[11];
    const float* bn2b   = (const float*)d_in[12];

    char* ws = (char*)d_ws;
    // layout (aliased by liveness):
    //   [0, 25.6MB)        h1 bf16 [50000,256]       (later h2 bf16 [50000,48] = 4.8MB)
    //   [25.6M, 51.2M)     x1 bf16 [50000,256]       (later x2 fp32 [50000,40] = 8MB)
    //   [52.0M, 58.4M)     srcs bucket ushort [50000,64] = 6.4MB
    //   [65.6M, +200KB)    cur int [50000] (degree counters)
    //   [66.0M, +4KB)      stats
    //   [76.8M, +128KB)    W1T bf16 [256,256]
    unsigned short* h1  = (unsigned short*)ws;
    unsigned short* x1  = (unsigned short*)(ws + 25600000);
    unsigned short* srcs = (unsigned short*)(ws + 52000000);
    int* cur            = (int*)(ws + 65600000);
    float* stats        = (float*)(ws + 66000000);
    unsigned short* w1t = (unsigned short*)(ws + 76800000);
    float* sum1   = stats;
    float* sumsq1 = stats + 256;
    float* sum2   = stats + 512;
    float* sumsq2 = stats + 576;
    unsigned short* h2 = (unsigned short*)ws;   // aliases dead h1
    float* x2 = (float*)(ws + 25600000);        // aliases dead x1
    float* out = (float*)d_out;

    // fused init: w1t transpose (blocks 0..255), zero cur (256..451), zero stats (452)
    init_kernel<<<453, 256, 0, stream>>>(W1, w1t, cur, stats);
    // bucket scatter (ushort payload)
    scatter_kernel<<<(N_EDGES + 255) / 256, 256, 0, stream>>>(ei, cur, srcs);

    // layer 1
    gemm1_mfma<<<dim3(391, 2), 256, 0, stream>>>(feat, w1t, b1, h1);
    agg1_kernel<<<(N_NODES + 3) / 4, 256, 0, stream>>>(h1, cur, srcs, gamma1, x1);
    stats1_kernel<<<1024, 256, 0, stream>>>(x1, sum1, sumsq1);

    // layer 2 (BN1+ReLU fused into gemm2; h2 bf16 stride 48, pad written by gemm2)
    gemm2_kernel<<<196, 256, 0, stream>>>(x1, W2, b2, sum1, sumsq1, bn1w, bn1b, h2);
    agg2_kernel<<<(N_NODES + 7) / 8, 256, 0, stream>>>(h2, cur, srcs, gamma2, x2);
    stats2_kernel<<<512, dim3(64, 4), 0, stream>>>(x2, sum2, sumsq2);
    final_kernel<<<(N_BATCH + 3) / 4, 256, 0, stream>>>(x2, sum2, sumsq2, bn2w, bn2b, batch, out);
}

// Round 10
// 345.533 us; speedup vs baseline: 1.3293x; 1.3293x over previous
//
#include <hip/hip_runtime.h>
#include <math.h>

#define N_NODES 50000
#define N_EDGES 800000
#define OUTC 40
#define N_BATCH 10000
#define H2S 48     // padded stride for h2 (bf16 elements)
#define BKT 64     // bucket slots per node (deg mean 16, sigma 4 -> 64 is ~12 sigma)
#define SP 16      // stats padding: one 64B line per channel (atomic de-serialization)

typedef float f32x4 __attribute__((ext_vector_type(4)));
typedef short s16x8 __attribute__((ext_vector_type(8)));
typedef short s16x4 __attribute__((ext_vector_type(4)));

union Frag { s16x8 v; s16x4 h[2]; };

__device__ inline unsigned short f2bf(float f) {
    unsigned int u = __float_as_uint(f);
    u += 0x7fff + ((u >> 16) & 1);           // round-to-nearest-even
    return (unsigned short)(u >> 16);
}
__device__ inline float lo16(unsigned int u) { return __uint_as_float(u << 16); }
__device__ inline float hi16(unsigned int u) { return __uint_as_float(u & 0xffff0000u); }
__device__ inline unsigned int pk2(float a, float b) {
    return (unsigned int)f2bf(a) | ((unsigned int)f2bf(b) << 16);
}
__device__ inline void unpk8(uint4 u, float* f) {   // 8 packed bf16 -> 8 fp32
    f[0] = lo16(u.x); f[1] = hi16(u.x);
    f[2] = lo16(u.y); f[3] = hi16(u.y);
    f[4] = lo16(u.z); f[5] = hi16(u.z);
    f[6] = lo16(u.w); f[7] = hi16(u.w);
}

// ---------------- fused init: W1T transpose + zero cur + zero padded stats ----------------
// stats layout (floats): sum1[256*SP] | sumsq1[256*SP] | sum2[40*SP] | sumsq2[40*SP] = 9472
__global__ __launch_bounds__(256) void init_kernel(const float* __restrict__ W1,
                                                   unsigned short* __restrict__ W1T,
                                                   int* __restrict__ cur,
                                                   float* __restrict__ stats) {
    int b = blockIdx.x, t = threadIdx.x;
    if (b < 256) {
        // W1 [256k][256n] fp32 -> W1T bf16 [256n][256k]
        W1T[(size_t)t * 256 + b] = f2bf(W1[(size_t)b * 256 + t]);
    } else if (b < 256 + 196) {
        int i = (b - 256) * 256 + t;
        if (i < N_NODES) cur[i] = 0;
    } else {
        int base = (b - 452) * 1184;
        for (int i = base + t; i < base + 1184; i += 256)
            if (i < 9472) stats[i] = 0.f;
    }
}

// ---------------- bucket scatter: cur[d] = degree, srcs[d*64+j] = j-th source (ushort) ----------------
__global__ __launch_bounds__(256) void scatter_kernel(const int* __restrict__ ei,
                                                      int* __restrict__ cur,
                                                      unsigned short* __restrict__ srcs) {
    int e = blockIdx.x * 256 + threadIdx.x;
    if (e >= N_EDGES) return;
    int d = ei[N_EDGES + e];
    int pos = atomicAdd(&cur[d], 1);
    if (pos < BKT) srcs[(size_t)d * BKT + pos] = (unsigned short)ei[e];
}

// ---------------- GEMM1 MFMA: h1 = bf16(feat @ W1 + b1), output bf16 ----------------
#define LDA 40
__global__ __launch_bounds__(256) void gemm1_mfma(const float* __restrict__ A,
                                                  const unsigned short* __restrict__ BT,
                                                  const float* __restrict__ bias,
                                                  unsigned short* __restrict__ C) {
    __shared__ unsigned short As[128 * LDA];
    __shared__ unsigned short Bs[128 * LDA];
    int t = threadIdx.x;
    int lane = t & 63, wave = t >> 6;
    int ln = lane & 15, quad = lane >> 4;
    int row0 = blockIdx.x * 128;
    int col0 = blockIdx.y * 128;
    int m0 = (wave & 1) * 64, n0 = (wave >> 1) * 64;
    f32x4 acc[4][4];
    #pragma unroll
    for (int i = 0; i < 4; i++)
        #pragma unroll
        for (int j = 0; j < 4; j++) acc[i][j] = (f32x4){0.f, 0.f, 0.f, 0.f};
    int r = t >> 1, half = t & 1;

    for (int k0 = 0; k0 < 256; k0 += 32) {
        {
            int gr = row0 + r;
            float4 v[4];
            if (gr < N_NODES) {
                const float4* src = (const float4*)(A + (size_t)gr * 256 + k0 + half * 16);
                v[0] = src[0]; v[1] = src[1]; v[2] = src[2]; v[3] = src[3];
            } else {
                float4 z = make_float4(0.f, 0.f, 0.f, 0.f);
                v[0] = z; v[1] = z; v[2] = z; v[3] = z;
            }
            ushort4* dst = (ushort4*)&As[r * LDA + half * 16];
            #pragma unroll
            for (int q = 0; q < 4; q++) {
                ushort4 u;
                u.x = f2bf(v[q].x); u.y = f2bf(v[q].y);
                u.z = f2bf(v[q].z); u.w = f2bf(v[q].w);
                dst[q] = u;
            }
        }
        {
            const ushort4* src = (const ushort4*)(BT + (size_t)(col0 + r) * 256 + k0 + half * 16);
            ushort4* dst = (ushort4*)&Bs[r * LDA + half * 16];
            dst[0] = src[0]; dst[1] = src[1]; dst[2] = src[2]; dst[3] = src[3];
        }
        __syncthreads();
        Frag af[4], bf[4];
        #pragma unroll
        for (int i = 0; i < 4; i++) {
            int ar = m0 + i * 16 + ln;
            af[i].h[0] = *(const s16x4*)&As[ar * LDA + quad * 8];
            af[i].h[1] = *(const s16x4*)&As[ar * LDA + quad * 8 + 4];
            int br = n0 + i * 16 + ln;
            bf[i].h[0] = *(const s16x4*)&Bs[br * LDA + quad * 8];
            bf[i].h[1] = *(const s16x4*)&Bs[br * LDA + quad * 8 + 4];
        }
        #pragma unroll
        for (int i = 0; i < 4; i++)
            #pragma unroll
            for (int j = 0; j < 4; j++)
                acc[i][j] = __builtin_amdgcn_mfma_f32_16x16x32_bf16(af[i].v, bf[j].v, acc[i][j], 0, 0, 0);
        __syncthreads();
    }
    #pragma unroll
    for (int j = 0; j < 4; j++) {
        int gc = col0 + n0 + j * 16 + ln;
        float bv = bias[gc];
        #pragma unroll
        for (int i = 0; i < 4; i++) {
            int gb = row0 + m0 + i * 16 + quad * 4;
            #pragma unroll
            for (int rg = 0; rg < 4; rg++) {
                int gr = gb + rg;
                if (gr < N_NODES) C[(size_t)gr * 256 + gc] = f2bf(acc[i][j][rg] + bv);
            }
        }
    }
}

// ---------------- agg1: wave per node, 4 edge-slots x 16 lanes (round-0 body) ----------------
__global__ __launch_bounds__(256) void agg1_kernel(const unsigned short* __restrict__ h,
                                                   const int* __restrict__ degp,
                                                   const unsigned short* __restrict__ srcs,
                                                   const float* __restrict__ gamma_p,
                                                   unsigned short* __restrict__ x1) {
    int lane = threadIdx.x & 63;
    int node = blockIdx.x * 4 + (threadIdx.x >> 6);
    if (node >= N_NODES) return;
    int eslot = lane >> 4, cgrp = lane & 15;
    float g = gamma_p[0];
    float hd[16];
    {
        const uint4* hrow = (const uint4*)(h + (size_t)node * 256 + cgrp * 16);
        uint4 u0 = hrow[0], u1 = hrow[1];
        unpk8(u0, hd); unpk8(u1, hd + 8);
    }
    float acc[16];
    #pragma unroll
    for (int c = 0; c < 16; c++) acc[c] = 0.f;
    float den = 0.f;
    int beg = node << 6;
    int end = beg + degp[node];
    int n_it = (end - beg + 3) >> 2;
    for (int it = 0; it < n_it; it++) {
        int i = beg + it * 4 + eslot;
        bool valid = i < end;
        int s = valid ? (int)srcs[i] : node;
        const uint4* arow = (const uint4*)(h + (size_t)s * 256 + cgrp * 16);
        uint4 u0 = arow[0], u1 = arow[1];
        float av[16];
        unpk8(u0, av); unpk8(u1, av + 8);
        float d2 = 0.f;
        #pragma unroll
        for (int c = 0; c < 16; c++) { float d = av[c] - hd[c]; d2 = fmaf(d, d, d2); }
        d2 += __shfl_xor(d2, 1, 64);
        d2 += __shfl_xor(d2, 2, 64);
        d2 += __shfl_xor(d2, 4, 64);
        d2 += __shfl_xor(d2, 8, 64);
        float w = valid ? __expf(-g * d2) : 0.f;
        den += w;
        #pragma unroll
        for (int c = 0; c < 16; c++) acc[c] = fmaf(w, av[c], acc[c]);
    }
    #pragma unroll
    for (int m = 16; m < 64; m <<= 1) {
        den += __shfl_xor(den, m, 64);
        #pragma unroll
        for (int c = 0; c < 16; c++) acc[c] += __shfl_xor(acc[c], m, 64);
    }
    if (eslot == 0) {
        float inv = 1.f / (den + 1e-16f);
        float vv[16];
        #pragma unroll
        for (int c = 0; c < 16; c++) vv[c] = acc[c] * inv;
        uint4 oA = make_uint4(pk2(vv[0], vv[1]), pk2(vv[2], vv[3]),
                              pk2(vv[4], vv[5]), pk2(vv[6], vv[7]));
        uint4 oB = make_uint4(pk2(vv[8], vv[9]), pk2(vv[10], vv[11]),
                              pk2(vv[12], vv[13]), pk2(vv[14], vv[15]));
        uint4* o4 = (uint4*)(x1 + (size_t)node * 256 + cgrp * 16);
        o4[0] = oA; o4[1] = oB;
    }
}

// ---------------- stats1: LDS block reduction, 1 atomic/channel/block, padded stats ----------------
// thread t: channel quad cg=(t&63)*4, row-stream rs=t>>6 (4 streams); uint2 loads (4 ch)
__global__ __launch_bounds__(256) void stats1_kernel(const unsigned short* __restrict__ x,
                                                     float* __restrict__ sum,
                                                     float* __restrict__ sumsq) {
    __shared__ float ls[4][256], lq[4][256];
    int t = threadIdx.x;
    int cg = (t & 63) * 4;
    int rs = t >> 6;
    float s0 = 0.f, s1 = 0.f, s2 = 0.f, s3 = 0.f;
    float q0 = 0.f, q1 = 0.f, q2 = 0.f, q3 = 0.f;
    for (int r = blockIdx.x * 4 + rs; r < N_NODES; r += gridDim.x * 4) {
        uint2 u = *(const uint2*)(x + (size_t)r * 256 + cg);
        float v0 = lo16(u.x), v1 = hi16(u.x), v2 = lo16(u.y), v3 = hi16(u.y);
        s0 += v0; q0 = fmaf(v0, v0, q0);
        s1 += v1; q1 = fmaf(v1, v1, q1);
        s2 += v2; q2 = fmaf(v2, v2, q2);
        s3 += v3; q3 = fmaf(v3, v3, q3);
    }
    ls[rs][cg] = s0; ls[rs][cg + 1] = s1; ls[rs][cg + 2] = s2; ls[rs][cg + 3] = s3;
    lq[rs][cg] = q0; lq[rs][cg + 1] = q1; lq[rs][cg + 2] = q2; lq[rs][cg + 3] = q3;
    __syncthreads();
    float S = ls[0][t] + ls[1][t] + ls[2][t] + ls[3][t];
    float Q = lq[0][t] + lq[1][t] + lq[2][t] + lq[3][t];
    atomicAdd(&sum[t * SP], S);
    atomicAdd(&sumsq[t * SP], Q);
}

// ---------------- GEMM2 + fused BN1/ReLU: h2 bf16(stride 48) = relu(bn(x1)) @ W2 + b2 ----------------
__global__ __launch_bounds__(256) void gemm2_kernel(const unsigned short* __restrict__ X,
                                                    const float* __restrict__ W2,
                                                    const float* __restrict__ bias,
                                                    const float* __restrict__ sum1,
                                                    const float* __restrict__ sumsq1,
                                                    const float* __restrict__ bg,
                                                    const float* __restrict__ bb,
                                                    unsigned short* __restrict__ H) {
    __shared__ float W2s[40 * 260];
    __shared__ float aas[256], bbs[256];
    int t = threadIdx.x;
    // coalesced staging: linear global read, scattered LDS write
    for (int i = t; i < 256 * 40; i += 256) {
        int k = i / 40, c = i % 40;       // W2 is [256k][40c] row-major
        W2s[c * 260 + k] = W2[i];
    }
    {
        const float invN = 1.f / N_NODES;
        float mu = sum1[t * SP] * invN;
        float var = sumsq1[t * SP] * invN - mu * mu;
        float rs = rsqrtf(var + 1e-5f) * bg[t];
        aas[t] = rs;
        bbs[t] = bb[t] - mu * rs;
    }
    __syncthreads();
    int slot = t >> 2, cg = t & 3;
    int rbase = blockIdx.x * 256 + slot;
    const uint2* xp[4];
    #pragma unroll
    for (int rr = 0; rr < 4; rr++) xp[rr] = (const uint2*)(X + (size_t)(rbase + rr * 64) * 256);
    float acc[4][10];
    #pragma unroll
    for (int rr = 0; rr < 4; rr++)
        #pragma unroll
        for (int i = 0; i < 10; i++) acc[rr][i] = 0.f;

    for (int k4 = 0; k4 < 64; k4++) {
        int k = k4 * 4;
        float4 a4 = *(const float4*)&aas[k];
        float4 b4 = *(const float4*)&bbs[k];
        float4 w4[10];
        #pragma unroll
        for (int i = 0; i < 10; i++) w4[i] = *(const float4*)&W2s[(cg * 10 + i) * 260 + k];
        #pragma unroll
        for (int rr = 0; rr < 4; rr++) {
            uint2 xu = xp[rr][k4];
            float y0 = fmaxf(fmaf(lo16(xu.x), a4.x, b4.x), 0.f);
            float y1 = fmaxf(fmaf(hi16(xu.x), a4.y, b4.y), 0.f);
            float y2 = fmaxf(fmaf(lo16(xu.y), a4.z, b4.z), 0.f);
            float y3 = fmaxf(fmaf(hi16(xu.y), a4.w, b4.w), 0.f);
            #pragma unroll
            for (int i = 0; i < 10; i++)
                acc[rr][i] += y0 * w4[i].x + y1 * w4[i].y + y2 * w4[i].z + y3 * w4[i].w;
        }
    }
    #pragma unroll
    for (int rr = 0; rr < 4; rr++) {
        int row = rbase + rr * 64;
        if (row < N_NODES) {
            float y[10];
            #pragma unroll
            for (int i = 0; i < 10; i++) y[i] = acc[rr][i] + bias[cg * 10 + i];
            unsigned int* o32 = (unsigned int*)(H + (size_t)row * H2S + cg * 10);
            #pragma unroll
            for (int i = 0; i < 5; i++) o32[i] = pk2(y[2 * i], y[2 * i + 1]);
            if (cg == 1)
                *(uint4*)(H + (size_t)row * H2S + 40) = make_uint4(0, 0, 0, 0);
        }
    }
}

// ---------------- agg2: 2 nodes per wave (half-wave = 4 edge-slots x 8 lanes) ----------------
__global__ __launch_bounds__(256) void agg2_kernel(const unsigned short* __restrict__ h,
                                                   const int* __restrict__ degp,
                                                   const unsigned short* __restrict__ srcs,
                                                   const float* __restrict__ gamma_p,
                                                   float* __restrict__ x2) {
    int l32 = threadIdx.x & 31;
    int node = blockIdx.x * 8 + (threadIdx.x >> 5);
    if (node >= N_NODES) return;
    int eslot = l32 >> 3, cgrp = l32 & 7;
    float g = gamma_p[0];
    float hd[6];
    {
        const unsigned int* hrow = (const unsigned int*)(h + (size_t)node * H2S + cgrp * 6);
        unsigned int u0 = hrow[0], u1 = hrow[1], u2 = hrow[2];
        hd[0] = lo16(u0); hd[1] = hi16(u0);
        hd[2] = lo16(u1); hd[3] = hi16(u1);
        hd[4] = lo16(u2); hd[5] = hi16(u2);
    }
    float acc[6] = {0.f, 0.f, 0.f, 0.f, 0.f, 0.f};
    float den = 0.f;
    int beg = node << 6;
    int end = beg + degp[node];
    int n_it = (end - beg + 3) >> 2;
    for (int it = 0; it < n_it; it++) {
        int i = beg + it * 4 + eslot;
        bool valid = i < end;
        int s = valid ? (int)srcs[i] : node;
        const unsigned int* arow = (const unsigned int*)(h + (size_t)s * H2S + cgrp * 6);
        unsigned int u0 = arow[0], u1 = arow[1], u2 = arow[2];
        float av[6];
        av[0] = lo16(u0); av[1] = hi16(u0);
        av[2] = lo16(u1); av[3] = hi16(u1);
        av[4] = lo16(u2); av[5] = hi16(u2);
        float d2 = 0.f;
        #pragma unroll
        for (int j = 0; j < 6; j++) { float d = av[j] - hd[j]; d2 = fmaf(d, d, d2); }
        d2 += __shfl_xor(d2, 1, 64);    // within 8-lane cgrp group
        d2 += __shfl_xor(d2, 2, 64);
        d2 += __shfl_xor(d2, 4, 64);
        float w = valid ? __expf(-g * d2) : 0.f;
        den += w;
        #pragma unroll
        for (int j = 0; j < 6; j++) acc[j] = fmaf(w, av[j], acc[j]);
    }
    // reduce across the 4 edge-slots of this half-wave (masks 8,16 stay in-half)
    #pragma unroll
    for (int m = 8; m < 32; m <<= 1) {
        den += __shfl_xor(den, m, 64);
        #pragma unroll
        for (int j = 0; j < 6; j++) acc[j] += __shfl_xor(acc[j], m, 64);
    }
    if (eslot == 0) {
        float inv = 1.f / (den + 1e-16f);
        int cb = cgrp * 6;
        #pragma unroll
        for (int j = 0; j < 6; j++)
            if (cb + j < OUTC) x2[(size_t)node * OUTC + cb + j] = acc[j] * inv;
    }
}

// ---------------- stats2: LDS block reduction, 1 atomic/channel/block, padded stats ----------------
// thread t<240: channel pair c2=(t%20)*2, row-stream rs=t/20 (12 streams); float2 loads
__global__ __launch_bounds__(256) void stats2_kernel(const float* __restrict__ x,
                                                     float* __restrict__ sum,
                                                     float* __restrict__ sumsq) {
    __shared__ float ls[12][40], lq[12][40];
    int t = threadIdx.x;
    if (t < 240) {
        int c2 = (t % 20) * 2;
        int rs = t / 20;
        float s0 = 0.f, s1 = 0.f, q0 = 0.f, q1 = 0.f;
        for (int r = blockIdx.x * 12 + rs; r < N_NODES; r += gridDim.x * 12) {
            float2 v = *(const float2*)(x + (size_t)r * OUTC + c2);
            s0 += v.x; q0 = fmaf(v.x, v.x, q0);
            s1 += v.y; q1 = fmaf(v.y, v.y, q1);
        }
        ls[rs][c2] = s0; ls[rs][c2 + 1] = s1;
        lq[rs][c2] = q0; lq[rs][c2 + 1] = q1;
    }
    __syncthreads();
    if (t < OUTC) {
        float S = 0.f, Q = 0.f;
        #pragma unroll
        for (int rs = 0; rs < 12; rs++) { S += ls[rs][t]; Q += lq[rs][t]; }
        atomicAdd(&sum[t * SP], S);
        atomicAdd(&sumsq[t * SP], Q);
    }
}

// ---------------- BN2 + ReLU + gather + log_softmax ----------------
__global__ __launch_bounds__(256) void final_kernel(const float* __restrict__ x2,
                                                    const float* __restrict__ sum,
                                                    const float* __restrict__ sumsq,
                                                    const float* __restrict__ g,
                                                    const float* __restrict__ b,
                                                    const int* __restrict__ batch,
                                                    float* __restrict__ out) {
    int lane = threadIdx.x & 63;
    int row = blockIdx.x * 4 + (threadIdx.x >> 6);
    if (row >= N_BATCH) return;
    int node = batch[row];
    bool act = lane < OUTC;
    float v = -INFINITY;
    if (act) {
        const float invN = 1.f / N_NODES;
        float mu = sum[lane * SP] * invN;
        float var = sumsq[lane * SP] * invN - mu * mu;
        float xv = x2[(size_t)node * OUTC + lane];
        float y = (xv - mu) * rsqrtf(var + 1e-5f) * g[lane] + b[lane];
        v = fmaxf(y, 0.f);
    }
    float m = v;
    #pragma unroll
    for (int s = 1; s < 64; s <<= 1) m = fmaxf(m, __shfl_xor(m, s, 64));
    float p = act ? expf(v - m) : 0.f;
    float ssum = p;
    #pragma unroll
    for (int s = 1; s < 64; s <<= 1) ssum += __shfl_xor(ssum, s, 64);
    if (act) out[(size_t)row * OUTC + lane] = v - m - logf(ssum);
}

extern "C" void kernel_launch(void* const* d_in, const int* in_sizes, int n_in,
                              void* d_out, int out_size, void* d_ws, size_t ws_size,
                              hipStream_t stream) {
    const float* feat   = (const float*)d_in[0];
    const int*   ei     = (const int*)d_in[1];
    const int*   batch  = (const int*)d_in[2];
    const float* W1     = (const float*)d_in[3];
    const float* b1     = (const float*)d_in[4];
    const float* gamma1 = (const float*)d_in[5];
    const float* W2     = (const float*)d_in[6];
    const float* b2     = (const float*)d_in[7];
    const float* gamma2 = (const float*)d_in[8];
    const float* bn1w   = (const float*)d_in[9];
    const float* bn1b   = (const float*)d_in[10];
    const float* bn2w   = (const float*)d_in[11];
    const float* bn2b   = (const float*)d_in[12];

    char* ws = (char*)d_ws;
    // layout (aliased by liveness):
    //   [0, 25.6MB)        h1 bf16 [50000,256]       (later h2 bf16 [50000,48] = 4.8MB)
    //   [25.6M, 51.2M)     x1 bf16 [50000,256]       (later x2 fp32 [50000,40] = 8MB)
    //   [52.0M, 58.4M)     srcs bucket ushort [50000,64] = 6.4MB
    //   [65.6M, +200KB)    cur int [50000] (degree counters)
    //   [66.0M, +38KB)     padded stats (9472 floats)
    //   [76.8M, +128KB)    W1T bf16 [256,256]
    unsigned short* h1  = (unsigned short*)ws;
    unsigned short* x1  = (unsigned short*)(ws + 25600000);
    unsigned short* srcs = (unsigned short*)(ws + 52000000);
    int* cur            = (int*)(ws + 65600000);
    float* stats        = (float*)(ws + 66000000);
    unsigned short* w1t = (unsigned short*)(ws + 76800000);
    float* sum1   = stats;                    // 256*SP floats
    float* sumsq1 = stats + 256 * SP;         // 256*SP floats
    float* sum2   = stats + 512 * SP;         // 40*SP floats
    float* sumsq2 = stats + 512 * SP + 40 * SP;
    unsigned short* h2 = (unsigned short*)ws;   // aliases dead h1
    float* x2 = (float*)(ws + 25600000);        // aliases dead x1
    float* out = (float*)d_out;

    // fused init: w1t transpose (0..255), zero cur (256..451), zero padded stats (452..459)
    init_kernel<<<460, 256, 0, stream>>>(W1, w1t, cur, stats);
    // bucket scatter (ushort payload)
    scatter_kernel<<<(N_EDGES + 255) / 256, 256, 0, stream>>>(ei, cur, srcs);

    // layer 1
    gemm1_mfma<<<dim3(391, 2), 256, 0, stream>>>(feat, w1t, b1, h1);
    agg1_kernel<<<(N_NODES + 3) / 4, 256, 0, stream>>>(h1, cur, srcs, gamma1, x1);
    stats1_kernel<<<256, 256, 0, stream>>>(x1, sum1, sumsq1);

    // layer 2 (BN1+ReLU fused into gemm2; h2 bf16 stride 48, pad written by gemm2)
    gemm2_kernel<<<196, 256, 0, stream>>>(x1, W2, b2, sum1, sumsq1, bn1w, bn1b, h2);
    agg2_kernel<<<(N_NODES + 7) / 8, 256, 0, stream>>>(h2, cur, srcs, gamma2, x2);
    stats2_kernel<<<256, 256, 0, stream>>>(x2, sum2, sumsq2);
    final_kernel<<<(N_BATCH + 3) / 4, 256, 0, stream>>>(x2, sum2, sumsq2, bn2w, bn2b, batch, out);
}